// Round 5
// baseline (374.990 us; speedup 1.0000x reference)
//
#include <hip/hip_runtime.h>
#include <math.h>

// ---------------- geometry constants ----------------
#define NXg      192
#define PLANE_SZ (NXg*NXg)            // 36864
#define PLANES   16                   // B(2) * NR(8)
#define TOTAL    (PLANES*PLANE_SZ)
#define NT       200
#define NM       32
#define CW       96                   // central window width
#define C0       48                   // central window origin
#define W96SQ    (CW*CW)
#define A0       24                   // active domain [24,168)^2 ; outside ~0 (coef 9e-14)
#define TILE     36                   // interior tile, 16 tiles/plane -> 256 blocks
#define HALO     16                   // 2 cells/step * 8 steps
#define EXPW     68                   // TILE + 2*HALO
#define LSTR     72                   // LDS row stride
#define LROWS    72                   // 2 pad + 68 + 2 pad
#define KSTEP    8
#define NLAUNCH  25

struct MeasIdx { int v[NM]; };
typedef float4 f4;
typedef float2 f2;

// LDS-only barrier: skip the vmcnt(0) drain __syncthreads would emit.
// All cross-thread data is in LDS (lgkmcnt); global loads are consumed by the
// issuing thread (compiler inserts vmcnt waits before use).
__device__ __forceinline__ void barrier_lds(){
    asm volatile("s_waitcnt lgkmcnt(0)\n\ts_barrier" ::: "memory");
}

// rf = 1 - (bg/x)^2 over the central window, per batch (B=2); once per call
__global__ void rf_kernel(const float* __restrict__ x, float* __restrict__ rf){
    int i = blockIdx.x*blockDim.x + threadIdx.x;
    if (i < 2*W96SQ){ float t = 1.5f/x[i]; rf[i] = 1.0f - t*t; }
}

// identical arithmetic/order to the verified round-1..4 kernel
__device__ __forceinline__ f4 frow(f2 L, f4 C, f2 Q,
                                   f4 m2, f4 m1, f4 p1, f4 p2,
                                   f4 O, f4 CF, f4 RF, f4 D2)
{
    const float s = 1.0f/12.0f;
    float v0=L.x, v1=L.y, v2=C.x, v3=C.y, v4=C.z, v5=C.w, v6=Q.x, v7=Q.y;
    float lxA = (-v0 + 16.f*v1 - 30.f*v2 + 16.f*v3 - v4)*s;
    float lxB = (-v1 + 16.f*v2 - 30.f*v3 + 16.f*v4 - v5)*s;
    float lxC = (-v2 + 16.f*v3 - 30.f*v4 + 16.f*v5 - v6)*s;
    float lxD = (-v3 + 16.f*v4 - 30.f*v5 + 16.f*v6 - v7)*s;
    float lyA = (-m2.x + 16.f*m1.x - 30.f*v2 + 16.f*p1.x - p2.x)*s;
    float lyB = (-m2.y + 16.f*m1.y - 30.f*v3 + 16.f*p1.y - p2.y)*s;
    float lyC = (-m2.z + 16.f*m1.z - 30.f*v4 + 16.f*p1.z - p2.z)*s;
    float lyD = (-m2.w + 16.f*m1.w - 30.f*v5 + 16.f*p1.w - p2.w)*s;
    f4 r;
    r.x = 2.f*v2 - O.x + CF.x*(lxA+lyA) + RF.x*D2.x;
    r.y = 2.f*v3 - O.y + CF.y*(lxB+lyB) + RF.y*D2.y;
    r.z = 2.f*v4 - O.z + CF.z*(lxC+lyC) + RF.z*D2.z;
    r.w = 2.f*v5 - O.w + CF.w*(lxD+lyD) + RF.w*D2.w;
    return r;
}

// d2 = c - 2b + a, same expression shape as the old d2_kernel (bit-identical)
__device__ __forceinline__ f4 d2c(f4 c, f4 b, f4 a){
    f4 r;
    r.x = c.x - 2.f*b.x + a.x;
    r.y = c.y - 2.f*b.y + a.y;
    r.z = c.z - 2.f*b.z + a.z;
    r.w = c.w - 2.f*b.w + a.w;
    return r;
}

// Advance KSTEP steps of a 36x36 interior tile of one plane, in LDS.
// d2 folded in: register-rolled P0 time levels (Pa=P0[jj], Pb=P0[jj-1]).
__global__ __launch_bounds__(512, 2)
void step_fused(const float* __restrict__ RA, const float* __restrict__ RB,
                float* __restrict__ WA, float* __restrict__ WB,
                const float* __restrict__ P0, const float* __restrict__ rf,
                float* __restrict__ out, int J, MeasIdx meas)
{
    __shared__ float lds0[LROWS*LSTR];
    __shared__ float lds1[LROWS*LSTR];
    const int tid = threadIdx.x;
    const int pl  = blockIdx.x >> 4;          // plane = b*8 + r
    const int t   = blockIdx.x & 15;
    const int ty  = t >> 2, tx = t & 3;
    const int gy0 = A0 + ty*TILE - HALO;      // always in [8,184)
    const int gx0 = A0 + tx*TILE - HALO;
    const int b   = pl >> 3, rch = pl & 7;
    const size_t pbase = (size_t)pl * PLANE_SZ;

    // ---- load EXPW x EXPW tiles of both time levels ----
    for (int i = tid; i < EXPW*(EXPW/4); i += 512){   // 68*17 = 1156 f4 groups
        int ly = i/17, lx4 = (i%17)*4;
        size_t go = pbase + (size_t)(gy0+ly)*NXg + (gx0+lx4);
        *(f4*)&lds0[(ly+2)*LSTR + lx4] = *(const f4*)&RA[go];
        *(f4*)&lds1[(ly+2)*LSTR + lx4] = *(const f4*)&RB[go];
    }

    // ---- per-thread sub-block setup (2 rows x 4 cols; 34x17 = 578 sub-blocks) ----
    int oC[2], pofs[2], sMax[2];
    bool winv[2];
    f4 cfa[2], cfb[2], rfa[2], rfbv[2];
#pragma unroll
    for (int gi=0; gi<2; ++gi){
        int g = tid + gi*512;
        bool val = (g < 578);
        int gg = val ? g : 0;
        int sby = gg/17, sbx = gg%17;
        int ly0 = 2*sby, lx0 = 4*sbx;
        oC[gi] = (ly0+2)*LSTR + lx0;          // +2: top pad rows
        int s1 = (ly0-1) >> 1;
        int s2 = (65-ly0) >> 1;
        int s3 = (lx0+1) >> 1;
        int s4 = (65-lx0) >> 1;
        int sm = min(min(s1,s2), min(s3,s4));
        sMax[gi] = val ? sm : -1;
        int gy = gy0 + ly0, gx = gx0 + lx0;   // absolute coords
        bool win = (gy>=C0 && gy<C0+CW && gx>=C0 && gx<C0+CW);
        winv[gi] = win;
        pofs[gi] = win ? (gy*NXg + gx) : 0;   // absolute offset into a P0 slice
        if (win){
            const float* rp = rf + ((size_t)b*CW + (gy-C0))*CW + (gx-C0);
            rfa [gi] = *(const f4*)rp;
            rfbv[gi] = *(const f4*)(rp + CW);
        } else {
            rfa [gi] = make_float4(0.f,0.f,0.f,0.f);
            rfbv[gi] = rfa[gi];
        }
        float c0v[4], c1v[4];
#pragma unroll
        for (int ii=0; ii<4; ++ii){
            int gxr = gx + ii;
            bool ix = (gxr>=25 && gxr<167);
            float g0 = 0.3f * ((ix && gy  >=25 && gy  <167) ? 1.5f : 1e-6f);
            float g1 = 0.3f * ((ix && gy+1>=25 && gy+1<167) ? 1.5f : 1e-6f);
            c0v[ii] = g0*g0;
            c1v[ii] = g1*g1;
        }
        cfa[gi] = make_float4(c0v[0],c0v[1],c0v[2],c0v[3]);
        cfb[gi] = make_float4(c1v[0],c1v[1],c1v[2],c1v[3]);
    }

    // ---- receiver ownership, hoisted out of the step loop ----
    bool own = false; int loff = 0; size_t obase = 0;
    if (tid < NM){
        int rv = meas.v[tid];
        int ry = rv / NXg, rx = rv % NXg;
        int dy = ry - (A0 + ty*TILE), dx = rx - (A0 + tx*TILE);
        own = ((unsigned)dy < TILE) && ((unsigned)dx < TILE);
        loff = (dy+HALO+2)*LSTR + (dx+HALO);
        obase = ((size_t)pl*NM + tid)*NT;
    }

    // ---- P0 register chain init: Pa=P0[J], Pb=P0[J-1], D=d2[J] ----
    const float* P0r = P0 + (size_t)rch*NT*PLANE_SZ;
    f4 Pa0[2],Pa1[2],Pb0[2],Pb1[2],D0r[2],D1r[2];
#pragma unroll
    for (int gi=0; gi<2; ++gi){
        f4 z = make_float4(0.f,0.f,0.f,0.f);
        Pa0[gi]=z; Pa1[gi]=z; Pb0[gi]=z; Pb1[gi]=z; D0r[gi]=z; D1r[gi]=z;
        if (winv[gi]){
            const float* p = P0r + (size_t)J*PLANE_SZ + pofs[gi];
            Pa0[gi] = *(const f4*)p;
            Pa1[gi] = *(const f4*)(p + NXg);
            if (J >= 1){
                Pb0[gi] = *(const f4*)(p - PLANE_SZ);
                Pb1[gi] = *(const f4*)(p - PLANE_SZ + NXg);
            }
            if (J >= 2){
                f4 Pc0 = *(const f4*)(p - 2*PLANE_SZ);
                f4 Pc1 = *(const f4*)(p - 2*PLANE_SZ + NXg);
                D0r[gi] = d2c(Pa0[gi], Pb0[gi], Pc0);
                D1r[gi] = d2c(Pa1[gi], Pb1[gi], Pc1);
            }
        }
    }

    barrier_lds();

    // center rows of both levels, register-carried
    f4 OA0[2], OA1[2], OB0[2], OB1[2];
#pragma unroll
    for (int gi=0; gi<2; ++gi){
        OA0[gi] = *(const f4*)&lds0[oC[gi]];
        OA1[gi] = *(const f4*)&lds0[oC[gi]+LSTR];
        OB0[gi] = *(const f4*)&lds1[oC[gi]];
        OB1[gi] = *(const f4*)&lds1[oC[gi]+LSTR];
    }

#pragma unroll
    for (int s=0; s<KSTEP; ++s){
        float* pa = (s&1) ? lds1 : lds0;      // level being overwritten with p_s
        float* pb = (s&1) ? lds0 : lds1;      // stencil source p_{s-1}
#pragma unroll
        for (int gi=0; gi<2; ++gi){
            if (s <= sMax[gi]){
                int c = oC[gi];
                f4 C0r = (s&1) ? OA0[gi] : OB0[gi];   // pb center rows (own)
                f4 C1r = (s&1) ? OA1[gi] : OB1[gi];
                f4 O0  = (s&1) ? OB0[gi] : OA0[gi];   // pa center rows (p_{s-2})
                f4 O1  = (s&1) ? OB1[gi] : OA1[gi];
                f4 Rm2 = *(const f4*)&pb[c - 2*LSTR];
                f4 Rm1 = *(const f4*)&pb[c -   LSTR];
                f4 Rp2 = *(const f4*)&pb[c + 2*LSTR];
                f4 Rp3 = *(const f4*)&pb[c + 3*LSTR];
                f2 L0  = *(const f2*)&pb[c - 2];
                f2 L1  = *(const f2*)&pb[c + LSTR - 2];
                f2 Q0  = *(const f2*)&pb[c + 4];
                f2 Q1  = *(const f2*)&pb[c + LSTR + 4];
                f4 N0 = frow(L0, C0r, Q0, Rm2, Rm1, C1r, Rp2, O0, cfa[gi], rfa[gi],  D0r[gi]);
                f4 N1 = frow(L1, C1r, Q1, Rm1, C0r, Rp2, Rp3, O1, cfb[gi], rfbv[gi], D1r[gi]);
                *(f4*)&pa[c]        = N0;
                *(f4*)&pa[c + LSTR] = N1;
                if (s&1){ OB0[gi]=N0; OB1[gi]=N1; } else { OA0[gi]=N0; OA1[gi]=N1; }
            }
            // prefetch P0 slice for step s+1 and roll the d2 chain
            if (s+1 < KSTEP && winv[gi] && (s+1) <= sMax[gi]){
                const float* p = P0r + (size_t)(J+s+1)*PLANE_SZ + pofs[gi];
                f4 C0n = *(const f4*)p;
                f4 C1n = *(const f4*)(p + NXg);
                if (J+s+1 >= 2){
                    D0r[gi] = d2c(C0n, Pa0[gi], Pb0[gi]);
                    D1r[gi] = d2c(C1n, Pa1[gi], Pb1[gi]);
                } else {
                    f4 z = make_float4(0.f,0.f,0.f,0.f);
                    D0r[gi]=z; D1r[gi]=z;
                }
                Pb0[gi]=Pa0[gi]; Pb1[gi]=Pa1[gi];
                Pa0[gi]=C0n;     Pa1[gi]=C1n;
            }
        }
        barrier_lds();
        // receiver gather: pa holds p_{J+s}
        if (own) out[obase + (J+s)] = pa[loff];
    }

    // ---- write back interior of the last two levels ----
    // KSTEP=8: s=7 (odd) wrote lds1 -> lds1 = newest p_{J+7}, lds0 = p_{J+6}
    for (int i = tid; i < TILE*(TILE/4); i += 512){   // 36*9 = 324 groups
        int r = i/9, c4 = (i%9)*4;
        size_t go = pbase + (size_t)(A0 + ty*TILE + r)*NXg + (A0 + tx*TILE + c4);
        int lo = (r+HALO+2)*LSTR + (c4+HALO);
        *(f4*)&WB[go] = *(const f4*)&lds1[lo];
        *(f4*)&WA[go] = *(const f4*)&lds0[lo];
    }
}

extern "C" void kernel_launch(void* const* d_in, const int* in_sizes, int n_in,
                              void* d_out, int out_size, void* d_ws, size_t ws_size,
                              hipStream_t stream)
{
    const float* x  = (const float*)d_in[0];   // (2,1,96,96) f32
    const float* P0 = (const float*)d_in[1];   // (1,8,200,192,192) f32
    float* out = (float*)d_out;                // (2,8,32,200) f32

    float* F   = (float*)d_ws;
    float* f0  = F;
    float* f1  = F + (size_t)TOTAL;
    float* f2p = F + 2*(size_t)TOTAL;
    float* f3p = F + 3*(size_t)TOTAL;
    float* rfb = F + 4*(size_t)TOTAL;

    // zero ALL four field buffers: outer cells are never written and must stay 0
    hipMemsetAsync(F, 0, (size_t)4*TOTAL*sizeof(float), stream);

    rf_kernel<<<(2*W96SQ+255)/256, 256, 0, stream>>>(x, rfb);

    MeasIdx meas;
    for (int k=0;k<NM;++k){
        double th = 2.0*M_PI*(double)k/(double)NM;
        int mx = (int)(96.0 + 70.0*cos(th));
        int my = (int)(96.0 + 70.0*sin(th));
        meas.v[k] = mx*NXg + my;
    }

    float *RA=f0, *RB=f1, *WA=f2p, *WB=f3p;
    for (int L=0; L<NLAUNCH; ++L){
        step_fused<<<256, 512, 0, stream>>>(RA,RB,WA,WB,P0,rfb,out,L*KSTEP,meas);
        float* tsw;
        tsw=RA; RA=WA; WA=tsw;
        tsw=RB; RB=WB; WB=tsw;
    }
}

// Round 6
// 237.234 us; speedup vs baseline: 1.5807x; 1.5807x over previous
//
#include <hip/hip_runtime.h>
#include <math.h>

// ---------------- geometry constants ----------------
#define NXg      192
#define PLANE_SZ (NXg*NXg)            // 36864
#define PLANES   16                   // B(2) * NR(8)
#define TOTAL    (PLANES*PLANE_SZ)
#define NT       200
#define NM       32
#define CW       96                   // central window width
#define C0       48                   // central window origin
#define W96SQ    (CW*CW)
#define A0       24                   // active domain [24,168)^2 ; outside ~0 (coef 9e-14)
#define TILE     36                   // interior tile, 16 tiles/plane -> 256 blocks
#define HALO     20                   // 2 cells/step * 10 steps
#define EXPW     76                   // TILE + 2*HALO
#define LSTR     84                   // LDS row stride (76 + 8 slack; 84%32=20 spreads banks)
#define KSTEP    10
#define NLAUNCH  20
#define NSB      (38*19)              // 722 sub-blocks (2 rows x 4 cols each)
#define BLK      768                  // 12 waves: every thread has <=1 sub-block

struct MeasIdx { int v[NM]; };
typedef float4 f4;
typedef float2 f2;

// rf = 1 - (bg/x)^2 over the central window, per batch (B=2); once per call
__global__ void rf_kernel(const float* __restrict__ x, float* __restrict__ rf){
    int i = blockIdx.x*blockDim.x + threadIdx.x;
    if (i < 2*W96SQ){ float t = 1.5f/x[i]; rf[i] = 1.0f - t*t; }
}

// identical arithmetic/order to the verified round-1..5 kernels
__device__ __forceinline__ f4 frow(f2 L, f4 C, f2 Q,
                                   f4 m2, f4 m1, f4 p1, f4 p2,
                                   f4 O, f4 CF, f4 RF, f4 D2)
{
    const float s = 1.0f/12.0f;
    float v0=L.x, v1=L.y, v2=C.x, v3=C.y, v4=C.z, v5=C.w, v6=Q.x, v7=Q.y;
    float lxA = (-v0 + 16.f*v1 - 30.f*v2 + 16.f*v3 - v4)*s;
    float lxB = (-v1 + 16.f*v2 - 30.f*v3 + 16.f*v4 - v5)*s;
    float lxC = (-v2 + 16.f*v3 - 30.f*v4 + 16.f*v5 - v6)*s;
    float lxD = (-v3 + 16.f*v4 - 30.f*v5 + 16.f*v6 - v7)*s;
    float lyA = (-m2.x + 16.f*m1.x - 30.f*v2 + 16.f*p1.x - p2.x)*s;
    float lyB = (-m2.y + 16.f*m1.y - 30.f*v3 + 16.f*p1.y - p2.y)*s;
    float lyC = (-m2.z + 16.f*m1.z - 30.f*v4 + 16.f*p1.z - p2.z)*s;
    float lyD = (-m2.w + 16.f*m1.w - 30.f*v5 + 16.f*p1.w - p2.w)*s;
    f4 r;
    r.x = 2.f*v2 - O.x + CF.x*(lxA+lyA) + RF.x*D2.x;
    r.y = 2.f*v3 - O.y + CF.y*(lxB+lyB) + RF.y*D2.y;
    r.z = 2.f*v4 - O.z + CF.z*(lxC+lyC) + RF.z*D2.z;
    r.w = 2.f*v5 - O.w + CF.w*(lxD+lyD) + RF.w*D2.w;
    return r;
}

// d2 = c - 2b + a, same expression shape as the verified d2_kernel
__device__ __forceinline__ f4 d2c(f4 c, f4 b, f4 a){
    f4 r;
    r.x = c.x - 2.f*b.x + a.x;
    r.y = c.y - 2.f*b.y + a.y;
    r.z = c.z - 2.f*b.z + a.z;
    r.w = c.w - 2.f*b.w + a.w;
    return r;
}

// Advance KSTEP=10 steps of a 36x36 interior tile of one plane, in LDS.
// One 2x4 sub-block per thread (722 of 768). d2 folded via register chain.
__global__ __launch_bounds__(BLK, 3)
void step_fused(const float* __restrict__ RA, const float* __restrict__ RB,
                float* __restrict__ WA, float* __restrict__ WB,
                const float* __restrict__ P0, const float* __restrict__ rf,
                float* __restrict__ out, int J, MeasIdx meas)
{
    __shared__ float lds0[EXPW*LSTR];
    __shared__ float lds1[EXPW*LSTR];
    const int tid = threadIdx.x;
    // XCD-chunk swizzle: all 16 tiles of a plane land on one XCD's L2
    const int sw  = ((blockIdx.x & 7) << 5) | (blockIdx.x >> 3);
    const int pl  = sw >> 4;                  // plane = b*8 + r
    const int t   = sw & 15;
    const int ty  = t >> 2, tx = t & 3;
    const int gy0 = A0 + ty*TILE - HALO;      // in [4,116]
    const int gx0 = A0 + tx*TILE - HALO;
    const int b   = pl >> 3, rch = pl & 7;
    const size_t pbase = (size_t)pl * PLANE_SZ;

    // ---- load EXPW x EXPW tiles of both time levels (rows 0..75 all real) ----
    for (int i = tid; i < EXPW*19; i += BLK){  // 76*19 = 1444 f4 groups
        int ly = i/19, lx4 = (i%19)*4;
        size_t go = pbase + (size_t)(gy0+ly)*NXg + (gx0+lx4);
        *(f4*)&lds0[ly*LSTR + lx4] = *(const f4*)&RA[go];
        *(f4*)&lds1[ly*LSTR + lx4] = *(const f4*)&RB[go];
    }

    // ---- per-thread sub-block setup ----
    const bool val = (tid < NSB);
    const int gg  = val ? tid : 0;
    const int sby = gg/19, sbx = gg%19;
    const int ly0 = 2*sby, lx0 = 4*sbx;
    const int oC  = ly0*LSTR + lx0;
    // valid region at step s: [2s+2, 73-2s] in both dims
    int s1 = (ly0-1) >> 1;
    int s2 = (73-ly0) >> 1;
    int s3 = (lx0+1) >> 1;
    int s4 = (73-lx0) >> 1;
    const int sMax = val ? min(min(s1,s2), min(s3,s4)) : -1;
    const int gy = gy0 + ly0, gx = gx0 + lx0;
    const bool win = (gy>=C0 && gy<C0+CW && gx>=C0 && gx<C0+CW);
    const int pofs = win ? (gy*NXg + gx) : 0;

    f4 rfa, rfb2;
    if (win){
        const float* rp = rf + ((size_t)b*CW + (gy-C0))*CW + (gx-C0);
        rfa  = *(const f4*)rp;
        rfb2 = *(const f4*)(rp + CW);
    } else {
        rfa = make_float4(0.f,0.f,0.f,0.f);
        rfb2 = rfa;
    }
    f4 cfa, cfb;
    {
        float c0v[4], c1v[4];
#pragma unroll
        for (int ii=0; ii<4; ++ii){
            int gxr = gx + ii;
            bool ix = (gxr>=25 && gxr<167);
            float g0 = 0.3f * ((ix && gy  >=25 && gy  <167) ? 1.5f : 1e-6f);
            float g1 = 0.3f * ((ix && gy+1>=25 && gy+1<167) ? 1.5f : 1e-6f);
            c0v[ii] = g0*g0;
            c1v[ii] = g1*g1;
        }
        cfa = make_float4(c0v[0],c0v[1],c0v[2],c0v[3]);
        cfb = make_float4(c1v[0],c1v[1],c1v[2],c1v[3]);
    }

    // ---- receiver ownership, hoisted ----
    bool own = false; int loff = 0; size_t obase = 0;
    if (tid < NM){
        int rv = meas.v[tid];
        int ry = rv / NXg, rx = rv % NXg;
        int dy = ry - (A0 + ty*TILE), dx = rx - (A0 + tx*TILE);
        own = ((unsigned)dy < TILE) && ((unsigned)dx < TILE);
        loff = (dy+HALO)*LSTR + (dx+HALO);
        obase = ((size_t)pl*NM + tid)*NT;
    }

    // ---- P0 register chain: Pa=P0[J], Pb=P0[J-1]; D = d2 for step 0 ----
    const float* P0r = P0 + (size_t)rch*NT*PLANE_SZ;
    f4 z4 = make_float4(0.f,0.f,0.f,0.f);
    f4 Pa0=z4, Pa1=z4, Pb0=z4, Pb1=z4, D0=z4, D1=z4;
    if (win){
        const float* p = P0r + (size_t)J*PLANE_SZ + pofs;
        Pa0 = *(const f4*)p;
        Pa1 = *(const f4*)(p + NXg);
        if (J >= 1){
            Pb0 = *(const f4*)(p - PLANE_SZ);
            Pb1 = *(const f4*)(p - PLANE_SZ + NXg);
        }
        if (J >= 2){
            f4 Pc0 = *(const f4*)(p - 2*PLANE_SZ);
            f4 Pc1 = *(const f4*)(p - 2*PLANE_SZ + NXg);
            D0 = d2c(Pa0, Pb0, Pc0);
            D1 = d2c(Pa1, Pb1, Pc1);
        }
    }

    __syncthreads();

    // center rows of both levels, register-carried
    f4 OA0 = *(const f4*)&lds0[oC];
    f4 OA1 = *(const f4*)&lds0[oC+LSTR];
    f4 OB0 = *(const f4*)&lds1[oC];
    f4 OB1 = *(const f4*)&lds1[oC+LSTR];

#pragma unroll
    for (int s=0; s<KSTEP; ++s){
        float* pa = (s&1) ? lds1 : lds0;      // level overwritten with p_{J+s}
        float* pb = (s&1) ? lds0 : lds1;      // stencil source p_{J+s-1}

        // issue next-step P0 loads early (latency hides under the stencil)
        const bool pre = (s+1 < KSTEP) && win && ((s+1) <= sMax);
        f4 Pn0 = z4, Pn1 = z4;
        if (pre){
            const float* p = P0r + (size_t)(J+s+1)*PLANE_SZ + pofs;
            Pn0 = *(const f4*)p;
            Pn1 = *(const f4*)(p + NXg);
        }

        if (s <= sMax){
            f4 C0r = (s&1) ? OA0 : OB0;       // pb center rows (own)
            f4 C1r = (s&1) ? OA1 : OB1;
            f4 O0  = (s&1) ? OB0 : OA0;       // pa center rows (p_{s-2})
            f4 O1  = (s&1) ? OB1 : OA1;
            f4 Rm2 = *(const f4*)&pb[oC - 2*LSTR];
            f4 Rm1 = *(const f4*)&pb[oC -   LSTR];
            f4 Rp2 = *(const f4*)&pb[oC + 2*LSTR];
            f4 Rp3 = *(const f4*)&pb[oC + 3*LSTR];
            f2 L0  = *(const f2*)&pb[oC - 2];
            f2 L1  = *(const f2*)&pb[oC + LSTR - 2];
            f2 Q0  = *(const f2*)&pb[oC + 4];
            f2 Q1  = *(const f2*)&pb[oC + LSTR + 4];
            f4 N0 = frow(L0, C0r, Q0, Rm2, Rm1, C1r, Rp2, O0, cfa, rfa,  D0);
            f4 N1 = frow(L1, C1r, Q1, Rm1, C0r, Rp2, Rp3, O1, cfb, rfb2, D1);
            *(f4*)&pa[oC]        = N0;
            *(f4*)&pa[oC + LSTR] = N1;
            if (s&1){ OB0=N0; OB1=N1; } else { OA0=N0; OA1=N1; }
        }

        // roll the d2 chain for step s+1
        if (pre){
            if (J+s+1 >= 2){
                D0 = d2c(Pn0, Pa0, Pb0);
                D1 = d2c(Pn1, Pa1, Pb1);
            } else {
                D0 = z4; D1 = z4;
            }
            Pb0 = Pa0; Pb1 = Pa1;
            Pa0 = Pn0; Pa1 = Pn1;
        }

        __syncthreads();
        // receiver gather: pa holds p_{J+s}
        if (own) out[obase + (J+s)] = pa[loff];
    }

    // ---- write back interior of the last two levels ----
    // KSTEP=10: s=9 (odd) wrote lds1 -> lds1 = newest p_{J+9}, lds0 = p_{J+8}
    for (int i = tid; i < TILE*(TILE/4); i += BLK){   // 36*9 = 324 groups
        int r = i/9, c4 = (i%9)*4;
        size_t go = pbase + (size_t)(A0 + ty*TILE + r)*NXg + (A0 + tx*TILE + c4);
        int lo = (r+HALO)*LSTR + (c4+HALO);
        *(f4*)&WB[go] = *(const f4*)&lds1[lo];
        *(f4*)&WA[go] = *(const f4*)&lds0[lo];
    }
}

extern "C" void kernel_launch(void* const* d_in, const int* in_sizes, int n_in,
                              void* d_out, int out_size, void* d_ws, size_t ws_size,
                              hipStream_t stream)
{
    const float* x  = (const float*)d_in[0];   // (2,1,96,96) f32
    const float* P0 = (const float*)d_in[1];   // (1,8,200,192,192) f32
    float* out = (float*)d_out;                // (2,8,32,200) f32

    float* F   = (float*)d_ws;
    float* f0  = F;
    float* f1  = F + (size_t)TOTAL;
    float* f2p = F + 2*(size_t)TOTAL;
    float* f3p = F + 3*(size_t)TOTAL;
    float* rfb = F + 4*(size_t)TOTAL;

    // zero ALL four field buffers: outer cells are never written and must stay 0
    hipMemsetAsync(F, 0, (size_t)4*TOTAL*sizeof(float), stream);

    rf_kernel<<<(2*W96SQ+255)/256, 256, 0, stream>>>(x, rfb);

    MeasIdx meas;
    for (int k=0;k<NM;++k){
        double th = 2.0*M_PI*(double)k/(double)NM;
        int mx = (int)(96.0 + 70.0*cos(th));
        int my = (int)(96.0 + 70.0*sin(th));
        meas.v[k] = mx*NXg + my;
    }

    float *RA=f0, *RB=f1, *WA=f2p, *WB=f3p;
    for (int L=0; L<NLAUNCH; ++L){
        step_fused<<<256, BLK, 0, stream>>>(RA,RB,WA,WB,P0,rfb,out,L*KSTEP,meas);
        float* tsw;
        tsw=RA; RA=WA; WA=tsw;
        tsw=RB; RB=WB; WB=tsw;
    }
}